// Round 3
// baseline (267.090 us; speedup 1.0000x reference)
//
#include <hip/hip_runtime.h>
#include <hip/hip_bf16.h>

using short8 = __attribute__((ext_vector_type(8))) short;
using f32x4  = __attribute__((ext_vector_type(4))) float;

static constexpr int NN = 50000;   // nodes
static constexpr int NE = 800000;  // edges
static constexpr int MPAD = 50048; // 782 * 64 padded rows for bf16 activations
static constexpr int NB2 = 256;    // dst buckets
static constexpr int BNODE = 196;  // nodes per bucket (256*196 = 50176 >= NN)
static constexpr int CAPB = 4096;  // bucket capacity (mean 3125, sigma ~56)
static constexpr int NCHB = 200;   // pass-A chunks
static constexpr int CHB = NE / NCHB;  // 4000 edges per chunk (exact)
// Feature-slab layout: activations stored as 4 slabs of 32 features
// (slab k holds features [32k,32k+32) for all MPAD rows). One slab = 3.2 MB
// -> L2-resident per XCD pair. Row-slice = 64 B = one cache line.
static constexpr int SLABN = MPAD * 32;      // ushorts per slab (1,601,536)
static constexpr int SLABW = SLABN / 2;      // u32 per slab
static constexpr int AGGRID = 12512;         // 3128 node-groups x 4 slices

__device__ __forceinline__ float clip100(float v) { return fminf(fmaxf(v, -100.f), 100.f); }
__device__ __forceinline__ unsigned short f2b(float v) {
    __hip_bfloat16 h = __float2bfloat16(v);
    return *reinterpret_cast<unsigned short*>(&h);
}
__device__ __forceinline__ float blo(unsigned int u) { return __uint_as_float(u << 16); }
__device__ __forceinline__ float bhi(unsigned int u) { return __uint_as_float(u & 0xFFFF0000u); }
__device__ __forceinline__ float b2f(unsigned short u) {
    return __uint_as_float(((unsigned int)u) << 16);
}

// ---------------- K1: bucket (blocks 0..199) || weight cvt (blocks 200..455) -
__global__ __launch_bounds__(256) void k_front(const int* __restrict__ idx,
                                               int2* __restrict__ epair,
                                               int* __restrict__ gcur,
                                               const float* __restrict__ W1,
                                               const float* __restrict__ W2,
                                               const float* __restrict__ Wg,
                                               unsigned short* __restrict__ Wt1,
                                               unsigned short* __restrict__ Wt2,
                                               unsigned short* __restrict__ Wgt) {
    __shared__ int ls[CHB], ld[CHB];
    __shared__ int bcnt[NB2], bb[NB2], bofs[NB2];
    const int tid = threadIdx.x;
    if (blockIdx.x < NCHB) {
        const int beg = blockIdx.x * CHB;
        for (int i = tid; i < CHB; i += 256) {
            ls[i] = idx[beg + i];
            ld[i] = idx[NE + beg + i];
        }
        bcnt[tid] = 0;
        __syncthreads();
        for (int i = tid; i < CHB; i += 256) atomicAdd(&bcnt[ld[i] / BNODE], 1);
        __syncthreads();
        bb[tid] = atomicAdd(&gcur[tid], bcnt[tid]);
        bofs[tid] = 0;
        __syncthreads();
        for (int i = tid; i < CHB; i += 256) {
            const int d = ld[i];
            const int p = d / BNODE;
            const int pos = atomicAdd(&bofs[p], 1);
            epair[p * CAPB + bb[p] + pos] = make_int2(ls[i], d);
        }
    } else {
        const int i = (blockIdx.x - NCHB) * 256 + tid;  // 0..65535
        if (i < 16384) {
            const int n = i >> 7, k = i & 127;
            Wt1[i] = f2b(W1[k * 128 + n]);
        } else if (i < 32768) {
            const int j = i - 16384;
            const int n = j >> 7, k = j & 127;
            Wt2[j] = f2b(W2[k * 128 + n]);
        } else {
            const int j = i - 32768;
            const int n = j >> 8, k = j & 255;
            Wgt[j] = f2b(Wg[k * 128 + n]);
        }
    }
}

// ---------------- K2: sortfill (blocks 0..255) || layer-1 GEMM (256..1037) ---
// mfma1 writes UNscaled bf16(clip(x)@W1) in slab layout (dinv applied
// per-edge in aggr1 -> no dinv dependency, overlaps with sortfill).
__global__ __launch_bounds__(256) void k_mid(const int2* __restrict__ epair,
                                             const int* __restrict__ gcur,
                                             int* __restrict__ rowptr,
                                             float* __restrict__ dinv,
                                             int* __restrict__ esrc,
                                             const float* __restrict__ x,
                                             const unsigned short* __restrict__ Wt,
                                             unsigned short* __restrict__ Cb) {
    __shared__ alignas(16) char smem[CAPB * 3 * 4 + 3 * 256 * 4];  // 52224 B union
    const int tid = threadIdx.x;
    if (blockIdx.x < NB2) {
        int* ls   = (int*)smem;
        int* ld   = ls + CAPB;
        int* srt  = ld + CAPB;
        int* cntL = srt + CAPB;
        int* sc   = cntL + 256;
        int* cur  = sc + 256;
        const int t = tid;
        const int b = blockIdx.x;
        sc[t] = gcur[t];
        __syncthreads();
        for (int off = 1; off < 256; off <<= 1) {
            const int add = (t >= off) ? sc[t - off] : 0;
            __syncthreads();
            sc[t] += add;
            __syncthreads();
        }
        const int ne = gcur[b];
        const int base = sc[b] - ne;  // exclusive prefix for bucket b
        const int nb0 = b * BNODE;
        const int nn = min(NN - nb0, BNODE);
        if (b == 0 && t == 0) rowptr[NN] = NE;

        for (int i = t; i < ne; i += 256) {
            const int2 p = epair[b * CAPB + i];
            ls[i] = p.x;
            ld[i] = p.y - nb0;  // node-local index in [0, nn)
        }
        cntL[t] = 0;
        __syncthreads();
        for (int i = t; i < ne; i += 256) atomicAdd(&cntL[ld[i]], 1);
        __syncthreads();
        sc[t] = cntL[t];
        __syncthreads();
        for (int off = 1; off < 256; off <<= 1) {
            const int add = (t >= off) ? sc[t - off] : 0;
            __syncthreads();
            sc[t] += add;
            __syncthreads();
        }
        const int excl = sc[t] - cntL[t];
        cur[t] = excl;
        if (t < nn) {
            rowptr[nb0 + t] = base + excl;
            dinv[nb0 + t] = rsqrtf(1.f + (float)cntL[t]);
        }
        __syncthreads();
        for (int i = t; i < ne; i += 256) {
            const int pos = atomicAdd(&cur[ld[i]], 1);
            srt[pos] = ls[i];
        }
        __syncthreads();
        for (int i = t; i < ne; i += 256) esrc[base + i] = srt[i];
    } else {
        unsigned short* wl = (unsigned short*)smem;  // 128 x 136 = 34816 B
#pragma unroll
        for (int j = tid; j < 2048; j += 256) {  // 2048 = 128 rows x 16 short8
            const int row = j >> 4, c8 = j & 15;
            *(short8*)(wl + row * 136 + c8 * 8) = *(const short8*)(Wt + row * 128 + c8 * 8);
        }
        __syncthreads();

        const int wv = tid >> 6;
        const int ln = tid & 63;
        const int l16 = ln & 15;
        const int qd = ln >> 4;
        const int rowb = (blockIdx.x - NB2) * 64 + wv * 16;
        const long arow = rowb + l16;
        const int kq = qd * 8;

        f32x4 acc[8];
#pragma unroll
        for (int i = 0; i < 8; ++i) acc[i] = (f32x4){0.f, 0.f, 0.f, 0.f};

#pragma unroll
        for (int kc = 0; kc < 4; ++kc) {
            short8 a = (short8){0, 0, 0, 0, 0, 0, 0, 0};
            if (arow < NN) {
                const float* fp = x + arow * 128 + kc * 32 + kq;
                const float4 f0 = *(const float4*)fp;
                const float4 f1 = *(const float4*)(fp + 4);
                a[0] = (short)f2b(clip100(f0.x));
                a[1] = (short)f2b(clip100(f0.y));
                a[2] = (short)f2b(clip100(f0.z));
                a[3] = (short)f2b(clip100(f0.w));
                a[4] = (short)f2b(clip100(f1.x));
                a[5] = (short)f2b(clip100(f1.y));
                a[6] = (short)f2b(clip100(f1.z));
                a[7] = (short)f2b(clip100(f1.w));
            }
#pragma unroll
            for (int nt = 0; nt < 8; ++nt) {
                const short8 b = *(const short8*)(wl + (nt * 16 + l16) * 136 + kc * 32 + kq);
                acc[nt] = __builtin_amdgcn_mfma_f32_16x16x32_bf16(a, b, acc[nt], 0, 0, 0);
            }
        }

        const int r0 = rowb + qd * 4;
#pragma unroll
        for (int r = 0; r < 4; ++r) {
            const int row = r0 + r;
            if (row < NN) {
#pragma unroll
                for (int nt = 0; nt < 8; ++nt) {
                    Cb[(long)(nt >> 1) * SLABN + (long)row * 32 + (nt & 1) * 16 + l16] =
                        f2b(acc[nt][r]);
                }
            }
        }
    }
}

// ---------------- layer-2 MFMA GEMM (K=128, slab A in / slab out, scaled) ----
__global__ __launch_bounds__(256) void k_mfma2(const unsigned short* __restrict__ Ab,
                                               const unsigned short* __restrict__ Wt,
                                               unsigned short* __restrict__ Cb,
                                               const float* __restrict__ dinv) {
    __shared__ unsigned short wl[128 * 136];
    const int tid = threadIdx.x;
#pragma unroll
    for (int j = tid; j < 2048; j += 256) {
        const int row = j >> 4, c8 = j & 15;
        *(short8*)(wl + row * 136 + c8 * 8) = *(const short8*)(Wt + row * 128 + c8 * 8);
    }
    __syncthreads();

    const int wv = tid >> 6;
    const int ln = tid & 63;
    const int l16 = ln & 15;
    const int qd = ln >> 4;
    const int rowb = blockIdx.x * 64 + wv * 16;
    const long arow = rowb + l16;
    const int kq = qd * 8;

    f32x4 acc[8];
#pragma unroll
    for (int i = 0; i < 8; ++i) acc[i] = (f32x4){0.f, 0.f, 0.f, 0.f};

#pragma unroll
    for (int kc = 0; kc < 4; ++kc) {
        const short8 a = *(const short8*)(Ab + (long)kc * SLABN + arow * 32 + kq);
#pragma unroll
        for (int nt = 0; nt < 8; ++nt) {
            const short8 b = *(const short8*)(wl + (nt * 16 + l16) * 136 + kc * 32 + kq);
            acc[nt] = __builtin_amdgcn_mfma_f32_16x16x32_bf16(a, b, acc[nt], 0, 0, 0);
        }
    }

    const int r0 = rowb + qd * 4;
#pragma unroll
    for (int r = 0; r < 4; ++r) {
        const int row = r0 + r;
        if (row < NN) {
            const float dv = dinv[row];
#pragma unroll
            for (int nt = 0; nt < 8; ++nt) {
                Cb[(long)(nt >> 1) * SLABN + (long)row * 32 + (nt & 1) * 16 + l16] =
                    f2b(acc[nt][r] * dv);
            }
        }
    }
}

// ---------------- gate MFMA (K=256, split-K LDS staging, slab A/h reads) -----
__global__ __launch_bounds__(256) void k_mfma_gate(const unsigned short* __restrict__ Ab,
                                                   const float* __restrict__ Af,
                                                   const unsigned short* __restrict__ Wt,
                                                   const float* __restrict__ bg,
                                                   float* __restrict__ out) {
    __shared__ unsigned short wl[128 * 136];   // one 128x128 K-half at a time
    const int tid = threadIdx.x;
    const int wv = tid >> 6;
    const int ln = tid & 63;
    const int l16 = ln & 15;
    const int qd = ln >> 4;
    const int rowb = blockIdx.x * 64 + wv * 16;
    const long arow = rowb + l16;
    const int kq = qd * 8;

    f32x4 acc[8];
#pragma unroll
    for (int i = 0; i < 8; ++i) acc[i] = (f32x4){0.f, 0.f, 0.f, 0.f};

    // phase 1: K = 0..127 (h part, bf16 slab A)
#pragma unroll
    for (int j = tid; j < 2048; j += 256) {
        const int row = j >> 4, c8 = j & 15;
        *(short8*)(wl + row * 136 + c8 * 8) = *(const short8*)(Wt + row * 256 + c8 * 8);
    }
    __syncthreads();
    {
#pragma unroll
        for (int kc = 0; kc < 4; ++kc) {
            const short8 a = *(const short8*)(Ab + (long)kc * SLABN + arow * 32 + kq);
#pragma unroll
            for (int nt = 0; nt < 8; ++nt) {
                const short8 b = *(const short8*)(wl + (nt * 16 + l16) * 136 + kc * 32 + kq);
                acc[nt] = __builtin_amdgcn_mfma_f32_16x16x32_bf16(a, b, acc[nt], 0, 0, 0);
            }
        }
    }
    __syncthreads();  // all phase-1 reads of wl complete before overwrite

    // phase 2: K = 128..255 (x part, converted f32 A)
#pragma unroll
    for (int j = tid; j < 2048; j += 256) {
        const int row = j >> 4, c8 = j & 15;
        *(short8*)(wl + row * 136 + c8 * 8) = *(const short8*)(Wt + row * 256 + 128 + c8 * 8);
    }
    __syncthreads();
    {
        const bool valid = arow < NN;
        const float* fp = Af + arow * 128 + kq;
#pragma unroll
        for (int kc = 0; kc < 4; ++kc) {
            short8 a = (short8){0, 0, 0, 0, 0, 0, 0, 0};
            if (valid) {
                const float4 f0 = *(const float4*)(fp + kc * 32);
                const float4 f1 = *(const float4*)(fp + kc * 32 + 4);
                a[0] = (short)f2b(clip100(f0.x));
                a[1] = (short)f2b(clip100(f0.y));
                a[2] = (short)f2b(clip100(f0.z));
                a[3] = (short)f2b(clip100(f0.w));
                a[4] = (short)f2b(clip100(f1.x));
                a[5] = (short)f2b(clip100(f1.y));
                a[6] = (short)f2b(clip100(f1.z));
                a[7] = (short)f2b(clip100(f1.w));
            }
#pragma unroll
            for (int nt = 0; nt < 8; ++nt) {
                const short8 b = *(const short8*)(wl + (nt * 16 + l16) * 136 + kc * 32 + kq);
                acc[nt] = __builtin_amdgcn_mfma_f32_16x16x32_bf16(a, b, acc[nt], 0, 0, 0);
            }
        }
    }

    const int r0 = rowb + qd * 4;
#pragma unroll
    for (int nt = 0; nt < 8; ++nt) {
        const int col = nt * 16 + l16;
        const float bgv = bg[col];
#pragma unroll
        for (int r = 0; r < 4; ++r) {
            const int row = r0 + r;
            if (row < NN) {
                const float g = 1.f / (1.f + __expf(-(acc[nt][r] + bgv)));
                const unsigned short hu =
                    Ab[(long)(nt >> 1) * SLABN + (long)row * 32 + (nt & 1) * 16 + l16];
                out[(long)row * 128 + col] = b2f(hu) * g;
            }
        }
    }
}

// ---------------- slab aggregation (4 edges / wave-instr, XCD-pinned slices) -
// slice k = (blk&7)>>1 pins each 3.2 MB slab to one XCD pair (L2-resident).
// Wave: quarter q = lane>>4 owns edge 4m+q; fp = lane&15 owns feature pair
// (2 bf16 as u32). Per edge: one 64 B line. Butterfly shfl_xor(16,32) merges.
template <bool RES, bool ESCALE>
__global__ __launch_bounds__(256) void k_aggr(const unsigned short* __restrict__ As,
                                              unsigned short* __restrict__ Hb,
                                              const int* __restrict__ rowptr,
                                              const int* __restrict__ esrc,
                                              const float* __restrict__ dinv,
                                              const float* __restrict__ bias,
                                              const float* __restrict__ x) {
    const int k   = (blockIdx.x & 7) >> 1;                          // slice 0..3
    const int ngp = ((blockIdx.x >> 3) << 1) | (blockIdx.x & 1);    // 0..3127
    const int lane = threadIdx.x & 63;
    const int q  = lane >> 4;
    const int fp = lane & 15;
    const unsigned int* Ak = (const unsigned int*)As + (long)k * SLABW;
    unsigned int* Hk = (unsigned int*)Hb + (long)k * SLABW;
    const float2 bv = ((const float2*)(bias + k * 32))[fp];

    const int d0 = ngp * 16 + (threadIdx.x >> 6) * 4;
#pragma unroll 1
    for (int j = 0; j < 4; ++j) {
        const int d = __builtin_amdgcn_readfirstlane(d0 + j);
        if (d >= NN) continue;
        const float dd = dinv[d];
        const int beg = rowptr[d];
        const int end = rowptr[d + 1];
        float ax = 0.f, ay = 0.f;
        int i = beg;
        for (; i + 8 <= end; i += 8) {
            const int s0 = esrc[i + 0], s1 = esrc[i + 1], s2 = esrc[i + 2], s3 = esrc[i + 3];
            const int s4 = esrc[i + 4], s5 = esrc[i + 5], s6 = esrc[i + 6], s7 = esrc[i + 7];
            {
                const int sa = (q & 1) ? s1 : s0;
                const int sb = (q & 1) ? s3 : s2;
                const int sv = (q & 2) ? sb : sa;
                const unsigned int u = Ak[(long)sv * 16 + fp];
                if (ESCALE) {
                    const float wa = (q & 1) ? dinv[s1] : dinv[s0];
                    const float wb = (q & 1) ? dinv[s3] : dinv[s2];
                    const float w = (q & 2) ? wb : wa;
                    ax = fmaf(blo(u), w, ax);
                    ay = fmaf(bhi(u), w, ay);
                } else {
                    ax += blo(u);
                    ay += bhi(u);
                }
            }
            {
                const int sa = (q & 1) ? s5 : s4;
                const int sb = (q & 1) ? s7 : s6;
                const int sv = (q & 2) ? sb : sa;
                const unsigned int u = Ak[(long)sv * 16 + fp];
                if (ESCALE) {
                    const float wa = (q & 1) ? dinv[s5] : dinv[s4];
                    const float wb = (q & 1) ? dinv[s7] : dinv[s6];
                    const float w = (q & 2) ? wb : wa;
                    ax = fmaf(blo(u), w, ax);
                    ay = fmaf(bhi(u), w, ay);
                } else {
                    ax += blo(u);
                    ay += bhi(u);
                }
            }
        }
        if (i + 4 <= end) {
            const int s0 = esrc[i + 0], s1 = esrc[i + 1], s2 = esrc[i + 2], s3 = esrc[i + 3];
            const int sa = (q & 1) ? s1 : s0;
            const int sb = (q & 1) ? s3 : s2;
            const int sv = (q & 2) ? sb : sa;
            const unsigned int u = Ak[(long)sv * 16 + fp];
            if (ESCALE) {
                const float wa = (q & 1) ? dinv[s1] : dinv[s0];
                const float wb = (q & 1) ? dinv[s3] : dinv[s2];
                const float w = (q & 2) ? wb : wa;
                ax = fmaf(blo(u), w, ax);
                ay = fmaf(bhi(u), w, ay);
            } else {
                ax += blo(u);
                ay += bhi(u);
            }
            i += 4;
        }
        const int r = end - i;
        if (r > 0) {  // masked partial quad (duplicate-clamp indices, zero weight)
            const int s0 = esrc[i];
            const int s1 = esrc[i + ((r > 1) ? 1 : 0)];
            const int s2 = esrc[i + ((r > 2) ? 2 : 0)];
            const int sa = (q & 1) ? s1 : s0;
            const int sv = (q & 2) ? s2 : sa;
            const unsigned int u = Ak[(long)sv * 16 + fp];
            float w = (q < r) ? 1.f : 0.f;
            if (ESCALE) {
                const float wa = (q & 1) ? dinv[s1] : dinv[s0];
                const float wsv = (q & 2) ? dinv[s2] : wa;
                w *= wsv;
            }
            ax = fmaf(blo(u), w, ax);
            ay = fmaf(bhi(u), w, ay);
        }
        // butterfly reduce across the 4 quarters
        ax += __shfl_xor(ax, 16);
        ax += __shfl_xor(ax, 32);
        ay += __shfl_xor(ay, 16);
        ay += __shfl_xor(ay, 32);
        // self term
        const unsigned int us = Ak[(long)d * 16 + fp];
        if (ESCALE) {
            ax = fmaf(blo(us), dd, ax);
            ay = fmaf(bhi(us), dd, ay);
        } else {
            ax += blo(us);
            ay += bhi(us);
        }
        float fx = fmaxf(fmaf(ax, dd, bv.x), 0.f);
        float fy = fmaxf(fmaf(ay, dd, bv.y), 0.f);
        if (RES) {
            const float2 xv = ((const float2*)(x + (long)d * 128 + k * 32))[fp];
            fx += clip100(xv.x);
            fy += clip100(xv.y);
        }
        if (lane < 16) {
            Hk[(long)d * 16 + fp] = (unsigned int)f2b(fx) | ((unsigned int)f2b(fy) << 16);
        }
    }
}

// ---------------- launch ----------------
extern "C" void kernel_launch(void* const* d_in, const int* in_sizes, int n_in,
                              void* d_out, int out_size, void* d_ws, size_t ws_size,
                              hipStream_t stream) {
    const float* x  = (const float*)d_in[0];
    const int*  eix = (const int*)d_in[1];
    const float* W1 = (const float*)d_in[2];
    const float* b1 = (const float*)d_in[3];
    const float* W2 = (const float*)d_in[4];
    const float* b2 = (const float*)d_in[5];
    const float* Wg = (const float*)d_in[6];
    const float* bg = (const float*)d_in[7];
    float* out = (float*)d_out;

    char* ws = (char*)d_ws;
    unsigned short* As   = (unsigned short*)ws;                     // 12,812,288 B (4 slabs)
    unsigned short* hb   = (unsigned short*)(ws + 12812288);        // 12,812,288 B (4 slabs)
    unsigned short* Wt1  = (unsigned short*)(ws + 25624576);        // 32,768 B
    unsigned short* Wt2  = (unsigned short*)(ws + 25657344);        // 32,768 B
    unsigned short* Wgt  = (unsigned short*)(ws + 25690112);        // 65,536 B
    int*   rowptr = (int*)(ws + 25755648);                          // 200,704 B
    float* dinv   = (float*)(ws + 25956352);                        // 200,704 B
    int*   gcur   = (int*)(ws + 26157056);                          // 1,024 B
    int*   esrc   = (int*)(ws + 26159104);                          // 3,200,000 B
    int2*  epair  = (int2*)(ws + 29359104);                         // 8,388,608 B
    // end ~37.7 MB

    const int ggrid = MPAD / 64;  // 782
    dim3 blk(256);

    hipMemsetAsync(gcur, 0, NB2 * sizeof(int), stream);

    // K1: CSR pass-A buckets (200 blocks) || weight convert (256 blocks)
    k_front<<<NCHB + 256, blk, 0, stream>>>(eix, epair, gcur, W1, W2, Wg, Wt1, Wt2, Wgt);

    // K2: CSR sort+rowptr+dinv (256 blocks) || layer-1 GEMM, unscaled slab (782)
    k_mid<<<NB2 + ggrid, blk, 0, stream>>>(epair, gcur, rowptr, dinv, esrc, x, Wt1, As);

    // layer 1 aggregate (slab, per-edge dinv[s])
    k_aggr<false, true><<<AGGRID, blk, 0, stream>>>(
        As, hb, rowptr, esrc, dinv, b1, nullptr);

    // layer 2 GEMM: As = bf16((h1 @ W2) * dinv_row), slab in/out
    k_mfma2<<<ggrid, blk, 0, stream>>>(hb, Wt2, As, dinv);

    // layer 2 aggregate (slab, pre-scaled) + residual
    k_aggr<true, false><<<AGGRID, blk, 0, stream>>>(
        As, hb, rowptr, esrc, dinv, b2, x);

    // gate: G = [hb | clip(x)] @ Wgt (K=256) ; out = b2f(hb) * sigmoid(G + bg)
    k_mfma_gate<<<ggrid, blk, 0, stream>>>(hb, x, Wgt, bg, out);
}